// Round 9
// baseline (266.668 us; speedup 1.0000x reference)
//
#include <hip/hip_runtime.h>
#include <hip/hip_bf16.h>
#include <math.h>

typedef __hip_bfloat16 bf16_t;
typedef __attribute__((ext_vector_type(8))) short short8;
typedef __attribute__((ext_vector_type(4))) float floatx4;

#define T_SEQ 2048
#define NB    4
#define NH    16
#define HD    64
#define C_DIM 1024
#define M_ROWS (NB * T_SEQ)   // 8192

// Q pre-scale: (1/sqrt(64)) * log2(e) so scores are in log2 units and
// P = exp2(s) directly (unnormalized softmax; shift cancels in O = sum(Pv)/sum(P)).
#define Q_SCALE 0.18033688011f

// ---------------------------------------------------------------- helpers
__device__ __forceinline__ void load_lds16(const bf16_t* g, bf16_t* l) {
    __builtin_amdgcn_global_load_lds(
        (const __attribute__((address_space(1))) void*)g,
        (__attribute__((address_space(3))) void*)l,
        16, 0, 0);
}

__device__ __forceinline__ floatx4 mfma16(short8 a, short8 b, floatx4 c) {
    return __builtin_amdgcn_mfma_f32_16x16x32_bf16(a, b, c, 0, 0, 0);
}

// ---------------------------------------------------------------- converts
__global__ void convert_x_kernel(const float* __restrict__ x, bf16_t* __restrict__ xb) {
    int i = blockIdx.x * 256 + threadIdx.x;   // one float4 per thread
    float4 v = reinterpret_cast<const float4*>(x)[i];
    union { bf16_t h[4]; short4 s4; } u;
    u.h[0] = __float2bfloat16(v.x);
    u.h[1] = __float2bfloat16(v.y);
    u.h[2] = __float2bfloat16(v.z);
    u.h[3] = __float2bfloat16(v.w);
    reinterpret_cast<short4*>(xb)[i] = u.s4;
}

// W [K,N] fp32 -> Wt [N,K] bf16, LDS-tiled transpose. block (32,8), grid (32,32,4)
__global__ void transpose_cvt_kernel(const float* __restrict__ W0, const float* __restrict__ W1,
                                     const float* __restrict__ W2, const float* __restrict__ W3,
                                     bf16_t* __restrict__ O0, bf16_t* __restrict__ O1,
                                     bf16_t* __restrict__ O2, bf16_t* __restrict__ O3) {
    const float* W = (blockIdx.z == 0) ? W0 : (blockIdx.z == 1) ? W1 : (blockIdx.z == 2) ? W2 : W3;
    bf16_t*      O = (blockIdx.z == 0) ? O0 : (blockIdx.z == 1) ? O1 : (blockIdx.z == 2) ? O2 : O3;
    __shared__ float tile[32][33];
    int bx = blockIdx.x * 32, by = blockIdx.y * 32;
    int tx = threadIdx.x, ty = threadIdx.y;
#pragma unroll
    for (int j = 0; j < 32; j += 8)
        tile[ty + j][tx] = W[(size_t)(by + ty + j) * C_DIM + bx + tx];
    __syncthreads();
#pragma unroll
    for (int j = 0; j < 32; j += 8)
        O[(size_t)(bx + ty + j) * C_DIM + by + tx] = __float2bfloat16(tile[tx][ty + j]);
}

// ---------------------------------------------------------------- GEMM mainloop
// C[128,128] += A[128,K] * Bt[128,K]^T  (both row-major, K-contiguous), BK=64.
// LDS layout XOR-swizzled: 16B piece p of row r lives at piece slot (p ^ (r&7)).
__device__ __forceinline__ void gemm_mainloop(const bf16_t* __restrict__ Ablk,
                                              const bf16_t* __restrict__ Bblk,
                                              bf16_t* As, bf16_t* Bs,
                                              floatx4 acc[4][4], int wave, int lane) {
    int lr = lane & 15, lq = lane >> 4;
    int wr = (wave >> 1) * 64, wc = (wave & 1) * 64;
    for (int kt = 0; kt < C_DIM; kt += 64) {
#pragma unroll
        for (int j = 0; j < 4; ++j) {
            int chunk = j * 256 + wave * 64 + lane;       // 0..1023, wave-contiguous
            int r = chunk >> 3, ps = chunk & 7;
            int c = ((ps ^ (r & 7)) * 8);                 // swizzled source column
            load_lds16(Ablk + (size_t)r * C_DIM + kt + c, As + chunk * 8);
            load_lds16(Bblk + (size_t)r * C_DIM + kt + c, Bs + chunk * 8);
        }
        __syncthreads();
#pragma unroll
        for (int kk = 0; kk < 2; ++kk) {
            short8 af[4], bfr[4];
            int psw = ((kk * 4 + lq) ^ (lr & 7)) * 8;     // swizzled piece offset
#pragma unroll
            for (int m = 0; m < 4; ++m)
                af[m] = *reinterpret_cast<const short8*>(As + (wr + m * 16 + lr) * 64 + psw);
#pragma unroll
            for (int n = 0; n < 4; ++n)
                bfr[n] = *reinterpret_cast<const short8*>(Bs + (wc + n * 16 + lr) * 64 + psw);
#pragma unroll
            for (int m = 0; m < 4; ++m)
#pragma unroll
                for (int n = 0; n < 4; ++n)
                    acc[m][n] = mfma16(af[m], bfr[n], acc[m][n]);
        }
        __syncthreads();
    }
}

// ---------------------------------------------------------------- QKV GEMM
// grid (8, 64, 3). Block->tile mapping is XCD-swizzled: f = x + 8y + 512z,
// xcd = f&7 owns row-panels [8*xcd, 8*xcd+8). Within an XCD, the A-panel
// index cycles FASTEST -> A (2 MB) stays L2-resident, W panels stream once.
__global__ __launch_bounds__(256, 3) void gemm_qkv_kernel(
    const bf16_t* __restrict__ xb,
    const bf16_t* __restrict__ WqT, const bf16_t* __restrict__ WkT, const bf16_t* __restrict__ WvT,
    const float* __restrict__ bq, const float* __restrict__ bk, const float* __restrict__ bv,
    bf16_t* __restrict__ Q, bf16_t* __restrict__ K, bf16_t* __restrict__ Vt) {
    __shared__ bf16_t As[128 * 64];
    __shared__ bf16_t Bs[128 * 64];
    int tid = threadIdx.x, wave = tid >> 6, lane = tid & 63;

    int f    = (int)blockIdx.x + ((int)blockIdx.y << 3) + ((int)blockIdx.z << 9);
    int xcd  = f & 7;
    int s    = f >> 3;          // 0..191 per-XCD sequence
    int rloc = s & 7;           // A-panel: fastest
    int t2   = s >> 3;          // 0..23
    int colp = t2 & 7;          // W-panel
    int wsel = t2 >> 3;         // 0..2: z outermost per XCD
    int row0 = (xcd * 8 + rloc) * 128;
    int col0 = colp * 128;

    const bf16_t* Wt  = (wsel == 0) ? WqT : (wsel == 1) ? WkT : WvT;
    const float* bias = (wsel == 0) ? bq : (wsel == 1) ? bk : bv;

    floatx4 acc[4][4] = {};
    gemm_mainloop(xb + (size_t)row0 * C_DIM, Wt + (size_t)col0 * C_DIM, As, Bs, acc, wave, lane);

    int lr = lane & 15, lq = lane >> 4;
    int wr = (wave >> 1) * 64, wc = (wave & 1) * 64;

    if (wsel == 2) {
        // V transposed store, packed short4 (8B)
#pragma unroll
        for (int nt = 0; nt < 4; ++nt) {
            int col = col0 + wc + nt * 16 + lr;
            float bvv = bias[col];
            int h = col >> 6, d = col & 63;
#pragma unroll
            for (int m = 0; m < 4; ++m) {
                int rowg0 = row0 + wr + m * 16 + lq * 4;
                int b = rowg0 >> 11, t0 = rowg0 & (T_SEQ - 1);
                union { bf16_t h4[4]; short4 s4; } u;
#pragma unroll
                for (int r = 0; r < 4; ++r)
                    u.h4[r] = __float2bfloat16(acc[m][nt][r] + bvv);
                *reinterpret_cast<short4*>(
                    &Vt[((size_t)((b * NH + h) * HD + d)) * T_SEQ + t0]) = u.s4;
            }
        }
    } else {
        float scale = (wsel == 0) ? Q_SCALE : 1.0f;
        bf16_t* outp = (wsel == 0) ? Q : K;
#pragma unroll
        for (int nt = 0; nt < 4; ++nt) {
            int col = col0 + wc + nt * 16 + lr;
            float bvv = bias[col];
            int h = col >> 6, d = col & 63;
#pragma unroll
            for (int m = 0; m < 4; ++m) {
#pragma unroll
                for (int r = 0; r < 4; ++r) {
                    int rowg = row0 + wr + m * 16 + lq * 4 + r;
                    int b = rowg >> 11, t = rowg & (T_SEQ - 1);
                    float val = (acc[m][nt][r] + bvv) * scale;
                    outp[((size_t)((b * NH + h) * T_SEQ + t)) * HD + d] =
                        __float2bfloat16(val);
                }
            }
        }
    }
}

// ---------------------------------------------------------------- attention
// Software-pipelined flash attention. grid (8,64), 512 thr = 8 waves, each
// wave owns 16 q-rows; two q-tiles per block (uniform 34 iters). K/V tiles
// TRIPLE-buffered in LDS; P double-buffered (Ps0/Ps1, compile-time identity
// via unroll-2). At iteration it: stage it+1, compute S_it/exp/write P_it,
// and do PV for P_{it-1} — whose LDS write was drained by the previous
// barrier (compiler emits lgkmcnt(0) before s_barrier), so the pf read has
// zero wait and PV+S MFMAs issue back-to-back. V_{it-1} still lives in the
// third buffer (prefetch only overwrites a tile dead for 2 iterations; all
// reads are consumed by MFMAs issued before the next barrier -> safe by
// barrier order, no timing assumptions). Post-loop PV drain + one barrier
// per pass. Accumulation order of o unchanged -> numerics identical to r8.
__device__ __forceinline__ void attn_iter(
    int it, int ktiles, int q0, int tid, int w, int lr, int lq,
    const bf16_t* __restrict__ Kbase, const bf16_t* __restrict__ Vbase,
    bf16_t* KsC, bf16_t* VsC, bf16_t* KsN, bf16_t* VsN, const bf16_t* VsP,
    unsigned short* PsW, const unsigned short* PsR,
    const short8 qf[2], floatx4 o[4], float lpart[4], bool do_pv)
{
    int kt0 = it * 64;
    __syncthreads();   // drains stage(it) vmcnt + last iter's P writes (lgkm)

    // prefetch tile it+1 into the buffer that held tile it-2 (dead)
    if (it + 1 < ktiles) {
        int nk0 = kt0 + 64;
        int ch = tid;
        int r = ch >> 3, ps = ch & 7;
        int c = ((ps ^ (r & 7)) * 8);
        load_lds16(Kbase + (size_t)(nk0 + r) * HD + c, KsN + ch * 8);
        load_lds16(Vbase + (size_t)r * T_SEQ + nk0 + c, VsN + ch * 8);
    }

    // issue deferred-PV loads first: P_{it-1} (drained) + V_{it-1} (3rd buf)
    short8 pf[2], vp[4][2];
    if (do_pv) {
        int prow = w * 16 + lr;
#pragma unroll
        for (int kk = 0; kk < 2; ++kk)
            pf[kk] = *reinterpret_cast<const short8*>(
                PsR + prow * 64 + (((kk * 4 + lq) ^ (lr & 7)) * 8));
#pragma unroll
        for (int kk = 0; kk < 2; ++kk) {
            int psw = ((kk * 4 + lq) ^ (lr & 7)) * 8;
#pragma unroll
            for (int dt = 0; dt < 4; ++dt)
                vp[dt][kk] = *reinterpret_cast<const short8*>(VsP + (dt * 16 + lr) * 64 + psw);
        }
    }
    // current K fragments
    short8 kf[4][2];
#pragma unroll
    for (int kk = 0; kk < 2; ++kk) {
        int psw = ((kk * 4 + lq) ^ (lr & 7)) * 8;
#pragma unroll
        for (int n = 0; n < 4; ++n)
            kf[n][kk] = *reinterpret_cast<const short8*>(KsC + (n * 16 + lr) * 64 + psw);
    }

    // PV for previous tile (its loads were issued earliest -> ready first)
    if (do_pv) {
#pragma unroll
        for (int kk = 0; kk < 2; ++kk)
#pragma unroll
            for (int dt = 0; dt < 4; ++dt)
                o[dt] = mfma16(pf[kk], vp[dt][kk], o[dt]);
    }

    // S = Q K^T (log2 units)
    floatx4 s[4] = {};
#pragma unroll
    for (int kk = 0; kk < 2; ++kk)
#pragma unroll
        for (int n = 0; n < 4; ++n)
            s[n] = mfma16(qf[kk], kf[n][kk], s[n]);

    // causal mask only on the last two tiles (block-uniform branch)
    if (it >= ktiles - 2) {
#pragma unroll
        for (int r = 0; r < 4; ++r) {
            int rowg = q0 + w * 16 + lq * 4 + r;
#pragma unroll
            for (int n = 0; n < 4; ++n) {
                int colg = kt0 + n * 16 + lr;
                if (colg > rowg) s[n][r] = -1e30f;
            }
        }
    }

    // P = exp2(s): single v_exp_f32; per-lane l partials
#pragma unroll
    for (int n = 0; n < 4; ++n)
#pragma unroll
        for (int r = 0; r < 4; ++r)
            s[n][r] = __builtin_amdgcn_exp2f(s[n][r]);
#pragma unroll
    for (int r = 0; r < 4; ++r)
        lpart[r] += (s[0][r] + s[1][r]) + (s[2][r] + s[3][r]);

    // write P_it (C-layout -> A-layout; rows wave-private; trunc-to-bf16).
    // Read back NEXT iteration, after the barrier's lgkm drain.
#pragma unroll
    for (int n = 0; n < 4; ++n)
#pragma unroll
        for (int r = 0; r < 4; ++r) {
            int prow = w * 16 + lq * 4 + r;
            int piece = n * 2 + (lr >> 3);
            union { float f; unsigned u; } cv; cv.f = s[n][r];
            PsW[prow * 64 + ((piece ^ (prow & 7)) * 8) + (lr & 7)] =
                (unsigned short)(cv.u >> 16);
        }
}

__global__ __launch_bounds__(512, 4) void attn_kernel(
    const bf16_t* __restrict__ Q, const bf16_t* __restrict__ K,
    const bf16_t* __restrict__ Vt, bf16_t* __restrict__ ctx) {
    __shared__ __align__(16) bf16_t Ks0[64 * 64], Ks1[64 * 64], Ks2[64 * 64];
    __shared__ __align__(16) bf16_t Vs0[64 * 64], Vs1[64 * 64], Vs2[64 * 64];
    __shared__ __align__(16) unsigned short Ps0[128 * 64], Ps1[128 * 64];
    int tid = threadIdx.x, w = tid >> 6, lane = tid & 63;
    int lr = lane & 15, lq = lane >> 4;
    int xcd = (int)blockIdx.x;
    int y   = (int)blockIdx.y;
    int bh  = xcd * 8 + (y & 7);      // XCD-local head group (4 MB K+V per XCD L2)
    int qp  = y >> 3;                 // 0..7 pass pair
    int b = bh >> 4, h = bh & 15;

    const bf16_t* Kbase = K  + (size_t)bh * T_SEQ * HD;
    const bf16_t* Vbase = Vt + (size_t)bh * HD * T_SEQ;

#pragma unroll 1
    for (int pass = 0; pass < 2; ++pass) {
        int qt = pass ? qp : (15 - qp);
        int q0 = qt * 128;
        int ktiles = 2 * qt + 2;                      // always even
        const bf16_t* Qbase = Q + ((size_t)bh * T_SEQ + q0) * HD;

        // stage tile 0 into buffer 0 (drained at the loop's first barrier)
        {
            int ch = tid;
            int r = ch >> 3, ps = ch & 7;
            int c = ((ps ^ (r & 7)) * 8);
            load_lds16(Kbase + (size_t)r * HD + c, Ks0 + ch * 8);
            load_lds16(Vbase + (size_t)r * T_SEQ + c, Vs0 + ch * 8);
        }

        // Q fragments in registers: wave w owns rows [w*16, w*16+16)
        short8 qf[2];
#pragma unroll
        for (int kk = 0; kk < 2; ++kk)
            qf[kk] = *reinterpret_cast<const short8*>(
                Qbase + (size_t)(w * 16 + lr) * HD + kk * 32 + lq * 8);

        floatx4 o[4] = {};
        float lpart[4] = {};

        // rotating triple-buffer pointers: C=cur, N=next(prefetch), P=prev
        bf16_t *KsC = Ks0, *KsN = Ks1, *KsP = Ks2;
        bf16_t *VsC = Vs0, *VsN = Vs1, *VsP = Vs2;

        for (int it2 = 0; it2 < ktiles; it2 += 2) {
            // even: writes Ps0, PV reads Ps1 (P_{it2-1})
            attn_iter(it2, ktiles, q0, tid, w, lr, lq, Kbase, Vbase,
                      KsC, VsC, KsN, VsN, VsP, Ps0, Ps1, qf, o, lpart, it2 > 0);
            { bf16_t* t = KsC; KsC = KsN; KsN = KsP; KsP = t; }
            { bf16_t* t = VsC; VsC = VsN; VsN = VsP; VsP = t; }
            // odd: writes Ps1, PV reads Ps0 (P_{it2})
            attn_iter(it2 + 1, ktiles, q0, tid, w, lr, lq, Kbase, Vbase,
                      KsC, VsC, KsN, VsN, VsP, Ps1, Ps0, qf, o, lpart, true);
            { bf16_t* t = KsC; KsC = KsN; KsN = KsP; KsP = t; }
            { bf16_t* t = VsC; VsC = VsN; VsN = VsP; VsP = t; }
        }

        // post-loop: PV for the final tile (P in Ps1; V tile in VsP after
        // the last rotation). One lgkm wait per pass — not per iteration.
        {
            int prow = w * 16 + lr;
            short8 pf[2], vp[4][2];
#pragma unroll
            for (int kk = 0; kk < 2; ++kk)
                pf[kk] = *reinterpret_cast<const short8*>(
                    Ps1 + prow * 64 + (((kk * 4 + lq) ^ (lr & 7)) * 8));
#pragma unroll
            for (int kk = 0; kk < 2; ++kk) {
                int psw = ((kk * 4 + lq) ^ (lr & 7)) * 8;
#pragma unroll
                for (int dt = 0; dt < 4; ++dt)
                    vp[dt][kk] = *reinterpret_cast<const short8*>(VsP + (dt * 16 + lr) * 64 + psw);
            }
#pragma unroll
            for (int kk = 0; kk < 2; ++kk)
#pragma unroll
                for (int dt = 0; dt < 4; ++dt)
                    o[dt] = mfma16(pf[kk], vp[dt][kk], o[dt]);
        }
        __syncthreads();   // all PV reads consumed before next pass restages

        // epilogue: reduce l across the 16 col-lanes (lane bits 0-3), normalize
#pragma unroll
        for (int r = 0; r < 4; ++r) {
            float l = lpart[r];
            l += __shfl_xor(l, 1);
            l += __shfl_xor(l, 2);
            l += __shfl_xor(l, 4);
            l += __shfl_xor(l, 8);
            float inv = 1.0f / l;
            int t = q0 + w * 16 + lq * 4 + r;
#pragma unroll
            for (int dt = 0; dt < 4; ++dt) {
                int d = dt * 16 + lr;
                ctx[((size_t)(b * T_SEQ + t)) * C_DIM + h * HD + d] =
                    __float2bfloat16(o[dt][r] * inv);
            }
        }
    }
}

// ---------------------------------------------------------------- output GEMM
// grid (8, 64), XCD-swizzled like gemm_qkv.
__global__ __launch_bounds__(256, 3) void gemm_out_kernel(
    const bf16_t* __restrict__ Actx, const bf16_t* __restrict__ WoT,
    const float* __restrict__ bo, float* __restrict__ out) {
    __shared__ bf16_t As[128 * 64];
    __shared__ bf16_t Bs[128 * 64];
    int tid = threadIdx.x, wave = tid >> 6, lane = tid & 63;

    int f    = (int)blockIdx.x + ((int)blockIdx.y << 3);
    int xcd  = f & 7;
    int s    = f >> 3;          // 0..63
    int rloc = s & 7;           // A-panel: fastest
    int colp = s >> 3;          // 0..7
    int row0 = (xcd * 8 + rloc) * 128;
    int col0 = colp * 128;

    floatx4 acc[4][4] = {};
    gemm_mainloop(Actx + (size_t)row0 * C_DIM, WoT + (size_t)col0 * C_DIM, As, Bs, acc, wave, lane);
    int lr = lane & 15, lq = lane >> 4;
    int wr = (wave >> 1) * 64, wc = (wave & 1) * 64;
#pragma unroll
    for (int nt = 0; nt < 4; ++nt) {
        int col = col0 + wc + nt * 16 + lr;
        float bvv = bo[col];
#pragma unroll
        for (int m = 0; m < 4; ++m)
#pragma unroll
            for (int r = 0; r < 4; ++r) {
                int rowg = row0 + wr + m * 16 + lq * 4 + r;
                out[(size_t)rowg * C_DIM + col] = acc[m][nt][r] + bvv;
            }
    }
}

// ---------------------------------------------------------------- launcher
extern "C" void kernel_launch(void* const* d_in, const int* in_sizes, int n_in,
                              void* d_out, int out_size, void* d_ws, size_t ws_size,
                              hipStream_t stream) {
    const float* x  = (const float*)d_in[0];
    const float* Wq = (const float*)d_in[1];
    const float* bq = (const float*)d_in[2];
    const float* Wk = (const float*)d_in[3];
    const float* bk = (const float*)d_in[4];
    const float* Wv = (const float*)d_in[5];
    const float* bv = (const float*)d_in[6];
    const float* Wo = (const float*)d_in[7];
    const float* bo = (const float*)d_in[8];
    float* out = (float*)d_out;

    char* ws = (char*)d_ws;
    bf16_t* xb  = (bf16_t*)ws; ws += (size_t)M_ROWS * C_DIM * 2;   // 16 MB
    bf16_t* WqT = (bf16_t*)ws; ws += (size_t)C_DIM * C_DIM * 2;    //  2 MB
    bf16_t* WkT = (bf16_t*)ws; ws += (size_t)C_DIM * C_DIM * 2;
    bf16_t* WvT = (bf16_t*)ws; ws += (size_t)C_DIM * C_DIM * 2;
    bf16_t* WoT = (bf16_t*)ws; ws += (size_t)C_DIM * C_DIM * 2;
    bf16_t* Qb  = (bf16_t*)ws; ws += (size_t)M_ROWS * C_DIM * 2;   // [B,H,T,D]
    bf16_t* Kb  = (bf16_t*)ws; ws += (size_t)M_ROWS * C_DIM * 2;   // [B,H,T,D]
    bf16_t* Vtb = (bf16_t*)ws; ws += (size_t)M_ROWS * C_DIM * 2;   // [B,H,D,T]
    bf16_t* ctx = (bf16_t*)ws; ws += (size_t)M_ROWS * C_DIM * 2;   // [B,T,C]

    convert_x_kernel<<<(M_ROWS * C_DIM / 4) / 256, 256, 0, stream>>>(x, xb);
    transpose_cvt_kernel<<<dim3(32, 32, 4), dim3(32, 8), 0, stream>>>(
        Wq, Wk, Wv, Wo, WqT, WkT, WvT, WoT);
    gemm_qkv_kernel<<<dim3(8, 64, 3), 256, 0, stream>>>(
        xb, WqT, WkT, WvT, bq, bk, bv, Qb, Kb, Vtb);
    attn_kernel<<<dim3(8, 64), 512, 0, stream>>>(Qb, Kb, Vtb, ctx);
    gemm_out_kernel<<<dim3(8, 64), 256, 0, stream>>>(ctx, WoT, bo, out);
}